// Round 1
// baseline (2453.216 us; speedup 1.0000x reference)
//
#include <hip/hip_runtime.h>
#include <math.h>

// Problem constants (fixed by the reference)
#define BB 4
#define SS 2048
#define DD 1024
#define HH 16
#define HD 64

// ---------------------------------------------------------------------------
// RoPE cos/sin table: [S][32] each.  inv_freq = 10000^(-j/32), angle = s*invf
// ---------------------------------------------------------------------------
__global__ void rope_table(float* __restrict__ cosT, float* __restrict__ sinT) {
    int idx = blockIdx.x * 256 + threadIdx.x;
    if (idx >= SS * 32) return;
    int s = idx >> 5;
    int j = idx & 31;
    float invf = powf(10000.0f, -(float)j / 32.0f);
    float ang = (float)s * invf;
    cosT[idx] = cosf(ang);
    sinT[idx] = sinf(ang);
}

// ---------------------------------------------------------------------------
// RoPE in-place on a [B*S, D] tensor laid out as (row, h*64+hd).
// Pair (j, j+32) within each head:  x1' = x1*c - x2*s ; x2' = x2*c + x1*s
// ---------------------------------------------------------------------------
__global__ void rope_apply(float* __restrict__ t,
                           const float* __restrict__ cosT,
                           const float* __restrict__ sinT) {
    int gid = blockIdx.x * 256 + threadIdx.x;     // B*S*512 pairs
    int row = gid >> 9;                            // 0 .. B*S-1
    int p = gid & 511;
    int h = p >> 5, j = p & 31;
    int s = row & (SS - 1);
    int c1 = (h << 6) + j;
    float c = cosT[(s << 5) + j];
    float sn = sinT[(s << 5) + j];
    size_t base = (size_t)row << 10;               // *D
    float x1 = t[base + c1];
    float x2 = t[base + c1 + 32];
    t[base + c1]      = x1 * c - x2 * sn;
    t[base + c1 + 32] = x2 * c + x1 * sn;
}

// ---------------------------------------------------------------------------
// fp32 GEMM, NT:  C[M,N] = A[M,K] * B[N,K]^T   (both row-major, contiguous K)
// 64x64 tile, BK=16, 256 threads, 4x4 per thread.
// LDS stored transposed [k][m] with stride 68 (16B-aligned rows, low conflict)
// ---------------------------------------------------------------------------
__global__ __launch_bounds__(256) void gemm_nt(const float* __restrict__ A,
                                               const float* __restrict__ Bm,
                                               float* __restrict__ C,
                                               int M, int N, int K) {
    __shared__ float As[16][68];
    __shared__ float Bs[16][68];
    const int t = threadIdx.x;
    const int row0 = blockIdx.y * 64;
    const int col0 = blockIdx.x * 64;
    const int tx = t & 15, ty = t >> 4;
    const int lr = t >> 2;            // 0..63
    const int lc = (t & 3) << 2;      // 0,4,8,12

    float acc[4][4] = {};

    for (int k0 = 0; k0 < K; k0 += 16) {
        float4 a4 = *reinterpret_cast<const float4*>(&A[(size_t)(row0 + lr) * K + k0 + lc]);
        float4 b4 = *reinterpret_cast<const float4*>(&Bm[(size_t)(col0 + lr) * K + k0 + lc]);
        __syncthreads();
        As[lc + 0][lr] = a4.x; As[lc + 1][lr] = a4.y; As[lc + 2][lr] = a4.z; As[lc + 3][lr] = a4.w;
        Bs[lc + 0][lr] = b4.x; Bs[lc + 1][lr] = b4.y; Bs[lc + 2][lr] = b4.z; Bs[lc + 3][lr] = b4.w;
        __syncthreads();
#pragma unroll
        for (int kk = 0; kk < 16; ++kk) {
            float4 av = *reinterpret_cast<const float4*>(&As[kk][ty << 2]);
            float4 bv = *reinterpret_cast<const float4*>(&Bs[kk][tx << 2]);
            float a[4] = {av.x, av.y, av.z, av.w};
            float b[4] = {bv.x, bv.y, bv.z, bv.w};
#pragma unroll
            for (int i = 0; i < 4; ++i)
#pragma unroll
                for (int j = 0; j < 4; ++j)
                    acc[i][j] = fmaf(a[i], b[j], acc[i][j]);
        }
    }
#pragma unroll
    for (int i = 0; i < 4; ++i) {
        float4 o4 = make_float4(acc[i][0], acc[i][1], acc[i][2], acc[i][3]);
        *reinterpret_cast<float4*>(&C[(size_t)(row0 + (ty << 2) + i) * N + col0 + (tx << 2)]) = o4;
    }
}

// ---------------------------------------------------------------------------
// Flash attention, fp32.  One block = 64 q rows of one (b,h).
// Q/K/V layout: [B*S, D] with head h at cols h*64..h*64+63.
// Online softmax; O written to `o` at the same rows/cols as Q was read
// (o may alias q: Q is consumed into LDS before any O write).
// ---------------------------------------------------------------------------
__device__ inline void fma4(float4& acc, float s, const float4& v) {
    acc.x = fmaf(s, v.x, acc.x);
    acc.y = fmaf(s, v.y, acc.y);
    acc.z = fmaf(s, v.z, acc.z);
    acc.w = fmaf(s, v.w, acc.w);
}

__global__ __launch_bounds__(256) void flash_attn(const float* __restrict__ q,
                                                  const float* __restrict__ k,
                                                  const float* __restrict__ v,
                                                  float* __restrict__ o) {
    __shared__ float Qs[64][68];
    __shared__ float Ks[64][68];
    __shared__ float Vs[64][68];
    __shared__ float Ps[64][68];
    const int t = threadIdx.x;
    const int qb = blockIdx.x, h = blockIdx.y, b = blockIdx.z;
    const int tx = t & 15, ty = t >> 4;
    const float scale = 0.125f;  // 1/sqrt(64)

    const size_t qrowbase = (size_t)(b * SS + qb * 64) * DD + h * HD;
    const int lr = t >> 2;
    const int lc0 = (t & 3) << 2;

    // stage Q (pre-scaled)
#pragma unroll
    for (int jj = 0; jj < 4; ++jj) {
        int c = lc0 + jj * 16;
        float4 val = *reinterpret_cast<const float4*>(&q[qrowbase + (size_t)lr * DD + c]);
        val.x *= scale; val.y *= scale; val.z *= scale; val.w *= scale;
        *reinterpret_cast<float4*>(&Qs[lr][c]) = val;
    }

    float m[4], l[4];
    float4 oacc[4];
#pragma unroll
    for (int i = 0; i < 4; ++i) {
        m[i] = -INFINITY; l[i] = 0.0f;
        oacc[i] = make_float4(0.f, 0.f, 0.f, 0.f);
    }

    const size_t kvhead = (size_t)b * SS * DD + h * HD;
    for (int kv0 = 0; kv0 < SS; kv0 += 64) {
        __syncthreads();   // previous iter done reading Ks/Vs/Ps; Qs staged
        {
            const size_t kb = kvhead + (size_t)(kv0 + lr) * DD;
#pragma unroll
            for (int jj = 0; jj < 4; ++jj) {
                int c = lc0 + jj * 16;
                *reinterpret_cast<float4*>(&Ks[lr][c]) = *reinterpret_cast<const float4*>(&k[kb + c]);
                *reinterpret_cast<float4*>(&Vs[lr][c]) = *reinterpret_cast<const float4*>(&v[kb + c]);
            }
        }
        __syncthreads();

        // scores: sc[i][j] = Qs[ty*4+i][:] . Ks[tx*4+j][:]
        float sc[4][4] = {};
#pragma unroll
        for (int d = 0; d < 64; d += 4) {
            float4 qv[4], kv4[4];
#pragma unroll
            for (int i = 0; i < 4; ++i) qv[i] = *reinterpret_cast<const float4*>(&Qs[(ty << 2) + i][d]);
#pragma unroll
            for (int j = 0; j < 4; ++j) kv4[j] = *reinterpret_cast<const float4*>(&Ks[(tx << 2) + j][d]);
#pragma unroll
            for (int i = 0; i < 4; ++i)
#pragma unroll
                for (int j = 0; j < 4; ++j)
                    sc[i][j] += qv[i].x * kv4[j].x + qv[i].y * kv4[j].y +
                                qv[i].z * kv4[j].z + qv[i].w * kv4[j].w;
        }

        // online softmax (row groups of 16 lanes share ty)
#pragma unroll
        for (int i = 0; i < 4; ++i) {
            float pm = fmaxf(fmaxf(sc[i][0], sc[i][1]), fmaxf(sc[i][2], sc[i][3]));
            pm = fmaxf(pm, __shfl_xor(pm, 1));
            pm = fmaxf(pm, __shfl_xor(pm, 2));
            pm = fmaxf(pm, __shfl_xor(pm, 4));
            pm = fmaxf(pm, __shfl_xor(pm, 8));
            float mn = fmaxf(m[i], pm);
            float al = expf(m[i] - mn);
            float p0 = expf(sc[i][0] - mn);
            float p1 = expf(sc[i][1] - mn);
            float p2 = expf(sc[i][2] - mn);
            float p3 = expf(sc[i][3] - mn);
            *reinterpret_cast<float4*>(&Ps[(ty << 2) + i][tx << 2]) = make_float4(p0, p1, p2, p3);
            float rs = p0 + p1 + p2 + p3;
            rs += __shfl_xor(rs, 1);
            rs += __shfl_xor(rs, 2);
            rs += __shfl_xor(rs, 4);
            rs += __shfl_xor(rs, 8);
            l[i] = l[i] * al + rs;
            m[i] = mn;
            oacc[i].x *= al; oacc[i].y *= al; oacc[i].z *= al; oacc[i].w *= al;
        }
        __syncthreads();

        // O += P * V  (thread cols = hd dims tx*4..+3)
#pragma unroll
        for (int kk = 0; kk < 64; kk += 4) {
            float4 vv[4];
#pragma unroll
            for (int x2 = 0; x2 < 4; ++x2)
                vv[x2] = *reinterpret_cast<const float4*>(&Vs[kk + x2][tx << 2]);
#pragma unroll
            for (int i = 0; i < 4; ++i) {
                float4 pp = *reinterpret_cast<const float4*>(&Ps[(ty << 2) + i][kk]);
                fma4(oacc[i], pp.x, vv[0]);
                fma4(oacc[i], pp.y, vv[1]);
                fma4(oacc[i], pp.z, vv[2]);
                fma4(oacc[i], pp.w, vv[3]);
            }
        }
    }

#pragma unroll
    for (int i = 0; i < 4; ++i) {
        float inv = 1.0f / l[i];
        float4 r4 = oacc[i];
        r4.x *= inv; r4.y *= inv; r4.z *= inv; r4.w *= inv;
        *reinterpret_cast<float4*>(&o[qrowbase + (size_t)((ty << 2) + i) * DD + (tx << 2)]) = r4;
    }
}

// ---------------------------------------------------------------------------
extern "C" void kernel_launch(void* const* d_in, const int* in_sizes, int n_in,
                              void* d_out, int out_size, void* d_ws, size_t ws_size,
                              hipStream_t stream) {
    const float* x  = (const float*)d_in[0];
    const float* Wq = (const float*)d_in[1];
    const float* Wk = (const float*)d_in[2];
    const float* Wv = (const float*)d_in[3];
    const float* Wo = (const float*)d_in[4];
    float* out = (float*)d_out;

    const size_t BSD = (size_t)BB * SS * DD;   // 8388608
    float* qb   = (float*)d_ws;
    float* kb   = qb + BSD;
    float* vb   = kb + BSD;
    float* cosT = vb + BSD;
    float* sinT = cosT + (size_t)SS * 32;
    float* ao   = qb;   // alias q buffer: flash_attn reads Q into LDS before writing O
    // ws needed: (3*BSD + 2*S*32)*4 B ~= 96.5 MiB

    const int M = BB * SS;                     // 8192
    dim3 blk(256);
    dim3 gg(DD / 64, M / 64);                  // (16, 128)

    hipLaunchKernelGGL(rope_table, dim3((SS * 32 + 255) / 256), blk, 0, stream, cosT, sinT);
    hipLaunchKernelGGL(gemm_nt, gg, blk, 0, stream, x, Wq, qb, M, DD, DD);
    hipLaunchKernelGGL(gemm_nt, gg, blk, 0, stream, x, Wk, kb, M, DD, DD);
    hipLaunchKernelGGL(gemm_nt, gg, blk, 0, stream, x, Wv, vb, M, DD, DD);
    hipLaunchKernelGGL(rope_apply, dim3(M * 512 / 256), blk, 0, stream, qb, cosT, sinT);
    hipLaunchKernelGGL(rope_apply, dim3(M * 512 / 256), blk, 0, stream, kb, cosT, sinT);
    hipLaunchKernelGGL(flash_attn, dim3(SS / 64, HH, BB), blk, 0, stream, qb, kb, vb, ao);
    hipLaunchKernelGGL(gemm_nt, gg, blk, 0, stream, ao, Wo, out, M, DD, DD);
}

// Round 2
// 437.704 us; speedup vs baseline: 5.6047x; 5.6047x over previous
//
#include <hip/hip_runtime.h>
#include <math.h>
#include <stdint.h>

#define BB 4
#define SS 2048
#define DDIM 1024
#define HH 16
#define HD 64

typedef __bf16 bf16x8 __attribute__((ext_vector_type(8)));
typedef float f32x4 __attribute__((ext_vector_type(4)));

// ---------------- helpers ----------------
__device__ __forceinline__ unsigned short f2bf(float f) {
    union { float f; unsigned u; } v; v.f = f;
    unsigned r = (v.u + 0x7FFFu + ((v.u >> 16) & 1u)) >> 16;
    return (unsigned short)r;
}
__device__ __forceinline__ float bf2f(unsigned short u) {
    union { unsigned u; float f; } v; v.u = ((unsigned)u) << 16;
    return v.f;
}
// async global(16B, per-lane addr) -> LDS(wave-uniform base + lane*16)
__device__ __forceinline__ void gload_lds16(const unsigned short* g, unsigned char* s) {
    __builtin_amdgcn_global_load_lds(
        (const __attribute__((address_space(1))) unsigned int*)(g),
        (__attribute__((address_space(3))) unsigned int*)(s), 16, 0, 0);
}

// ---------------- fp32 -> bf16 conversion ----------------
__global__ void cvt_f32_bf16(const float* __restrict__ in, unsigned short* __restrict__ outp, int n4) {
    int i = blockIdx.x * 256 + threadIdx.x;
    if (i >= n4) return;
    float4 v = ((const float4*)in)[i];
    ushort4 o;
    o.x = f2bf(v.x); o.y = f2bf(v.y); o.z = f2bf(v.z); o.w = f2bf(v.w);
    ((ushort4*)outp)[i] = o;
}

// ---------------- RoPE ----------------
__global__ void rope_table(float* __restrict__ cosT, float* __restrict__ sinT) {
    int idx = blockIdx.x * 256 + threadIdx.x;
    if (idx >= SS * 32) return;
    int s = idx >> 5;
    int j = idx & 31;
    float invf = powf(10000.0f, -(float)j / 32.0f);
    float ang = (float)s * invf;
    cosT[idx] = cosf(ang);
    sinT[idx] = sinf(ang);
}

__global__ void rope_bf16(unsigned short* __restrict__ t,
                          const float* __restrict__ cosT,
                          const float* __restrict__ sinT) {
    int gid = blockIdx.x * 256 + threadIdx.x;   // B*S*512 pairs
    int row = gid >> 9;
    int p = gid & 511;
    int h = p >> 5, j = p & 31;
    int s = row & (SS - 1);
    size_t base = ((size_t)row << 10) + (h << 6) + j;
    float c = cosT[(s << 5) + j], sn = sinT[(s << 5) + j];
    float x1 = bf2f(t[base]), x2 = bf2f(t[base + 32]);
    t[base]      = f2bf(x1 * c - x2 * sn);
    t[base + 32] = f2bf(x2 * c + x1 * sn);
}

// ---------------------------------------------------------------------------
// bf16 MFMA GEMM, NT: C[M,N] = A[M,K] * B[N,K]^T, fp32 accumulate.
// BM=BN=128, BK=32, 4 waves (2x2), 64x64 per wave = 4x4 16x16x32 frags.
// LDS: A tile [128][32]bf16 (64B rows) at 0, B tile at 8192.  Swizzle
// pi(o) = o ^ (((o>>7)&3)<<4) applied on stage-source and frag-read.
// ---------------------------------------------------------------------------
template <int OUT_BF16>
__global__ __launch_bounds__(256) void gemm_bf16_nt(const unsigned short* __restrict__ A,
                                                    const unsigned short* __restrict__ Bm,
                                                    void* __restrict__ C,
                                                    int M, int N, int K) {
    __shared__ unsigned char smem[16384];
    const int t = threadIdx.x;
    const int l = t & 63;
    const int w = t >> 6;
    const int wm = w >> 1, wn = w & 1;
    const int row0 = blockIdx.y * 128;
    const int col0 = blockIdx.x * 128;

    f32x4 zero4 = {0.f, 0.f, 0.f, 0.f};
    f32x4 acc[4][4];
#pragma unroll
    for (int i = 0; i < 4; ++i)
#pragma unroll
        for (int j = 0; j < 4; ++j) acc[i][j] = zero4;

    // staging geometry (per lane): dest o_rel = w*2048 + i*1024 + l*16
    const int srow = w * 32 + (l >> 2);                 // + i*16
    const int scol8 = ((l & 3) ^ ((l >> 3) & 3)) << 3;  // pre-swizzled source col (elems)

    for (int k0 = 0; k0 < K; k0 += 32) {
        __syncthreads();
        const unsigned short* aSrc = A + (size_t)(row0 + srow) * K + k0 + scol8;
        const unsigned short* bSrc = Bm + (size_t)(col0 + srow) * K + k0 + scol8;
        gload_lds16(aSrc,                     smem + w * 2048);
        gload_lds16(aSrc + (size_t)16 * K,    smem + w * 2048 + 1024);
        gload_lds16(bSrc,                     smem + 8192 + w * 2048);
        gload_lds16(bSrc + (size_t)16 * K,    smem + 8192 + w * 2048 + 1024);
        __syncthreads();

        bf16x8 af[4], bf[4];
#pragma unroll
        for (int mi = 0; mi < 4; ++mi) {
            int o1 = (wm * 64 + mi * 16 + (l & 15)) * 64 + ((l >> 4) << 4);
            o1 ^= ((o1 >> 7) & 3) << 4;
            af[mi] = *(const bf16x8*)(smem + o1);
        }
#pragma unroll
        for (int ni = 0; ni < 4; ++ni) {
            int o1 = (wn * 64 + ni * 16 + (l & 15)) * 64 + ((l >> 4) << 4);
            o1 ^= ((o1 >> 7) & 3) << 4;
            bf[ni] = *(const bf16x8*)(smem + 8192 + o1);
        }
#pragma unroll
        for (int mi = 0; mi < 4; ++mi)
#pragma unroll
            for (int ni = 0; ni < 4; ++ni)
                acc[mi][ni] = __builtin_amdgcn_mfma_f32_16x16x32_bf16(af[mi], bf[ni], acc[mi][ni], 0, 0, 0);
    }

    // epilogue: C/D layout col = l&15, row = (l>>4)*4 + r
    const int cr = (l >> 4) << 2;
    const int cc = l & 15;
#pragma unroll
    for (int mi = 0; mi < 4; ++mi) {
#pragma unroll
        for (int ni = 0; ni < 4; ++ni) {
            int gcol = col0 + wn * 64 + ni * 16 + cc;
#pragma unroll
            for (int r = 0; r < 4; ++r) {
                int grow = row0 + wm * 64 + mi * 16 + cr + r;
                if (OUT_BF16)
                    ((unsigned short*)C)[(size_t)grow * N + gcol] = f2bf(acc[mi][ni][r]);
                else
                    ((float*)C)[(size_t)grow * N + gcol] = acc[mi][ni][r];
            }
        }
    }
}

// ---------------------------------------------------------------------------
// MFMA flash attention (bf16 in, fp32 softmax/accum, bf16 out).
// Block: 128 q-rows of one (b,h); 4 waves x 32 q-rows. KV tiles of 64.
// LDS map (swz128: o ^= ((o>>7)&7)<<4, all bases 1KB-aligned):
//   Qs [0,16384)      128 x 128B   (global_load_lds, pre-swz source)
//   Ks [16384,24576)   64 x 128B   (global_load_lds, pre-swz source)
//   Vt [24576,32768)   64d x 128B  (reg-staged transpose: Vt[d][key])
//   Ps [32768,49152)   per wave 4KB: 32 q x 128B (wave-private)
// ---------------------------------------------------------------------------
__global__ __launch_bounds__(256) void attn_mfma(const unsigned short* __restrict__ qg,
                                                 const unsigned short* __restrict__ kg,
                                                 const unsigned short* __restrict__ vg,
                                                 unsigned short* __restrict__ og) {
    __shared__ unsigned char smem[49152];
    const int t = threadIdx.x;
    const int l = t & 63;
    const int w = t >> 6;
    const int qb0 = blockIdx.x * 128;
    const int h = blockIdx.y, b = blockIdx.z;
    const int headoff = h * HD;
    const float SC = 0.125f * 1.44269504089f;  // scale * log2(e)

    // ---- stage Q
    {
        const int col8 = ((l & 7) ^ (l >> 3)) << 3;
        const unsigned short* src = qg + (size_t)(b * SS + qb0 + w * 32 + (l >> 3)) * DDIM + headoff + col8;
#pragma unroll
        for (int i = 0; i < 4; ++i)
            gload_lds16(src + (size_t)(i * 8) * DDIM, smem + w * 4096 + i * 1024);
    }
    __syncthreads();

    // ---- Q A-frags into regs: rows w*32 + rf*16 + (l&15), d chunk kk
    bf16x8 qf[2][2];
#pragma unroll
    for (int rf = 0; rf < 2; ++rf)
#pragma unroll
        for (int kk = 0; kk < 2; ++kk) {
            int o1 = (w * 32 + rf * 16 + (l & 15)) * 128 + kk * 64 + ((l >> 4) << 4);
            o1 ^= ((o1 >> 7) & 7) << 4;
            qf[rf][kk] = *(const bf16x8*)(smem + o1);
        }

    f32x4 zero4 = {0.f, 0.f, 0.f, 0.f};
    f32x4 oacc[2][4];
    float mrow[2][4], lrow[2][4];
#pragma unroll
    for (int rf = 0; rf < 2; ++rf) {
#pragma unroll
        for (int df = 0; df < 4; ++df) oacc[rf][df] = zero4;
#pragma unroll
        for (int r = 0; r < 4; ++r) { mrow[rf][r] = -1e30f; lrow[rf][r] = 0.f; }
    }

    for (int kv0 = 0; kv0 < SS; kv0 += 64) {
        __syncthreads();  // prior iter finished reading Ks/Vt
        // ---- stage K tile (8KB; per wave 2KB)
        {
            const int col8 = ((l & 7) ^ (l >> 3)) << 3;
            const unsigned short* src = kg + (size_t)(b * SS + kv0 + w * 16 + (l >> 3)) * DDIM + headoff + col8;
            gload_lds16(src,                       smem + 16384 + w * 2048);
            gload_lds16(src + (size_t)8 * DDIM,    smem + 16384 + w * 2048 + 1024);
        }
        // ---- stage Vt (transposed, reg-staged)
        {
            const int kp = l & 31;             // key pair
            const int dblk = w * 2 + (l >> 5); // 0..7 -> d = dblk*8..+8
            const unsigned short* vsrc = vg + (size_t)(b * SS + kv0 + 2 * kp) * DDIM + headoff + dblk * 8;
            uint4 v0 = *(const uint4*)(vsrc);
            uint4 v1 = *(const uint4*)(vsrc + DDIM);
            const unsigned* A0 = (const unsigned*)&v0;
            const unsigned* A1 = (const unsigned*)&v1;
#pragma unroll
            for (int i2 = 0; i2 < 4; ++i2) {
                unsigned a = A0[i2], bb = A1[i2];
                unsigned p0 = (a & 0xffffu) | (bb << 16);
                unsigned p1 = (a >> 16) | (bb & 0xffff0000u);
                int d0 = dblk * 8 + 2 * i2;
                int o0 = (d0 * 128 + kp * 4) ^ ((d0 & 7) << 4);
                int o1b = ((d0 + 1) * 128 + kp * 4) ^ (((d0 + 1) & 7) << 4);
                *(unsigned*)(smem + 24576 + o0) = p0;
                *(unsigned*)(smem + 24576 + o1b) = p1;
            }
        }
        __syncthreads();  // K + V tiles visible

        // ---- S = Q K^T (frags: rf x kcol c, contract over d in 2 chunks)
        f32x4 sf[2][4];
#pragma unroll
        for (int rf = 0; rf < 2; ++rf)
#pragma unroll
            for (int c = 0; c < 4; ++c) sf[rf][c] = zero4;
#pragma unroll
        for (int kk = 0; kk < 2; ++kk) {
            bf16x8 kf4[4];
#pragma unroll
            for (int c = 0; c < 4; ++c) {
                int o1 = 16384 + (c * 16 + (l & 15)) * 128 + kk * 64 + ((l >> 4) << 4);
                o1 ^= ((o1 >> 7) & 7) << 4;
                kf4[c] = *(const bf16x8*)(smem + o1);
            }
#pragma unroll
            for (int rf = 0; rf < 2; ++rf)
#pragma unroll
                for (int c = 0; c < 4; ++c)
                    sf[rf][c] = __builtin_amdgcn_mfma_f32_16x16x32_bf16(qf[rf][kk], kf4[c], sf[rf][c], 0, 0, 0);
        }

        // ---- online softmax; P -> wave-private LDS (bf16, swz128)
#pragma unroll
        for (int rf = 0; rf < 2; ++rf) {
#pragma unroll
            for (int r = 0; r < 4; ++r) {
                float s0 = sf[rf][0][r] * SC, s1 = sf[rf][1][r] * SC;
                float s2 = sf[rf][2][r] * SC, s3 = sf[rf][3][r] * SC;
                float pm = fmaxf(fmaxf(s0, s1), fmaxf(s2, s3));
                pm = fmaxf(pm, __shfl_xor(pm, 1));
                pm = fmaxf(pm, __shfl_xor(pm, 2));
                pm = fmaxf(pm, __shfl_xor(pm, 4));
                pm = fmaxf(pm, __shfl_xor(pm, 8));
                float mn = fmaxf(mrow[rf][r], pm);
                float a2 = exp2f(mrow[rf][r] - mn);
                mrow[rf][r] = mn;
                float p0 = exp2f(s0 - mn), p1 = exp2f(s1 - mn);
                float p2 = exp2f(s2 - mn), p3 = exp2f(s3 - mn);
                int qrow = rf * 16 + ((l >> 4) << 2) + r;
                int obase = 32768 + w * 4096 + qrow * 128;
                int col2 = (l & 15) * 2;
                int sw = (qrow & 7) << 4;
                *(unsigned short*)(smem + ((obase + 0  + col2) ^ sw)) = f2bf(p0);
                *(unsigned short*)(smem + ((obase + 32 + col2) ^ sw)) = f2bf(p1);
                *(unsigned short*)(smem + ((obase + 64 + col2) ^ sw)) = f2bf(p2);
                *(unsigned short*)(smem + ((obase + 96 + col2) ^ sw)) = f2bf(p3);
                float rs = p0 + p1 + p2 + p3;
                rs += __shfl_xor(rs, 1);
                rs += __shfl_xor(rs, 2);
                rs += __shfl_xor(rs, 4);
                rs += __shfl_xor(rs, 8);
                lrow[rf][r] = lrow[rf][r] * a2 + rs;
                // rescale O
#pragma unroll
                for (int df = 0; df < 4; ++df) oacc[rf][df][r] *= a2;
            }
        }

        // ---- O += P V  (A = P from Ps, B = Vt)
#pragma unroll
        for (int kk = 0; kk < 2; ++kk) {
            bf16x8 pf[2], vf[4];
#pragma unroll
            for (int rf = 0; rf < 2; ++rf) {
                int o1 = 32768 + w * 4096 + (rf * 16 + (l & 15)) * 128 + kk * 64 + ((l >> 4) << 4);
                o1 ^= ((o1 >> 7) & 7) << 4;
                pf[rf] = *(const bf16x8*)(smem + o1);
            }
#pragma unroll
            for (int df = 0; df < 4; ++df) {
                int o1 = 24576 + (df * 16 + (l & 15)) * 128 + kk * 64 + ((l >> 4) << 4);
                o1 ^= ((o1 >> 7) & 7) << 4;
                vf[df] = *(const bf16x8*)(smem + o1);
            }
#pragma unroll
            for (int rf = 0; rf < 2; ++rf)
#pragma unroll
                for (int df = 0; df < 4; ++df)
                    oacc[rf][df] = __builtin_amdgcn_mfma_f32_16x16x32_bf16(pf[rf], vf[df], oacc[rf][df], 0, 0, 0);
        }
    }

    // ---- epilogue
#pragma unroll
    for (int rf = 0; rf < 2; ++rf) {
#pragma unroll
        for (int r = 0; r < 4; ++r) {
            float inv = 1.0f / lrow[rf][r];
            int qrow = qb0 + w * 32 + rf * 16 + ((l >> 4) << 2) + r;
            size_t base = (size_t)(b * SS + qrow) * DDIM + headoff + (l & 15);
#pragma unroll
            for (int df = 0; df < 4; ++df)
                og[base + df * 16] = f2bf(oacc[rf][df][r] * inv);
        }
    }
}

// ---------------------------------------------------------------------------
extern "C" void kernel_launch(void* const* d_in, const int* in_sizes, int n_in,
                              void* d_out, int out_size, void* d_ws, size_t ws_size,
                              hipStream_t stream) {
    const float* x  = (const float*)d_in[0];
    const float* Wq = (const float*)d_in[1];
    const float* Wk = (const float*)d_in[2];
    const float* Wv = (const float*)d_in[3];
    const float* Wo = (const float*)d_in[4];
    float* out = (float*)d_out;

    const size_t BSD = (size_t)BB * SS * DDIM;  // 8388608
    const size_t WSZ = (size_t)DDIM * DDIM;     // 1048576

    unsigned short* xb  = (unsigned short*)d_ws;
    unsigned short* wqb = xb + BSD;
    unsigned short* wkb = wqb + WSZ;
    unsigned short* wvb = wkb + WSZ;
    unsigned short* wob = wvb + WSZ;
    unsigned short* qb  = wob + WSZ;
    unsigned short* kb  = qb + BSD;
    unsigned short* vb  = kb + BSD;
    float* cosT = (float*)(vb + BSD);
    float* sinT = cosT + (size_t)SS * 32;
    unsigned short* ob = qb;  // attention output aliases qb (safe: Q consumed first)

    const int M = BB * SS;  // 8192
    dim3 blk(256);
    dim3 gg(DDIM / 128, M / 128);  // (8, 64)

    hipLaunchKernelGGL(rope_table, dim3((SS * 32 + 255) / 256), blk, 0, stream, cosT, sinT);
    hipLaunchKernelGGL(cvt_f32_bf16, dim3((unsigned)(BSD / 4 / 256)), blk, 0, stream, x, xb, (int)(BSD / 4));
    hipLaunchKernelGGL(cvt_f32_bf16, dim3((unsigned)(WSZ / 4 / 256)), blk, 0, stream, Wq, wqb, (int)(WSZ / 4));
    hipLaunchKernelGGL(cvt_f32_bf16, dim3((unsigned)(WSZ / 4 / 256)), blk, 0, stream, Wk, wkb, (int)(WSZ / 4));
    hipLaunchKernelGGL(cvt_f32_bf16, dim3((unsigned)(WSZ / 4 / 256)), blk, 0, stream, Wv, wvb, (int)(WSZ / 4));
    hipLaunchKernelGGL(cvt_f32_bf16, dim3((unsigned)(WSZ / 4 / 256)), blk, 0, stream, Wo, wob, (int)(WSZ / 4));

    hipLaunchKernelGGL((gemm_bf16_nt<1>), gg, blk, 0, stream, xb, wqb, (void*)qb, M, DDIM, DDIM);
    hipLaunchKernelGGL((gemm_bf16_nt<1>), gg, blk, 0, stream, xb, wkb, (void*)kb, M, DDIM, DDIM);
    hipLaunchKernelGGL((gemm_bf16_nt<1>), gg, blk, 0, stream, xb, wvb, (void*)vb, M, DDIM, DDIM);

    hipLaunchKernelGGL(rope_bf16, dim3(M * 512 / 256), blk, 0, stream, qb, cosT, sinT);
    hipLaunchKernelGGL(rope_bf16, dim3(M * 512 / 256), blk, 0, stream, kb, cosT, sinT);

    hipLaunchKernelGGL(attn_mfma, dim3(SS / 128, HH, BB), blk, 0, stream, qb, kb, vb, ob);

    hipLaunchKernelGGL((gemm_bf16_nt<0>), gg, blk, 0, stream, ob, wob, (void*)out, M, DDIM, DDIM);
}

// Round 3
// 306.713 us; speedup vs baseline: 7.9984x; 1.4271x over previous
//
#include <hip/hip_runtime.h>
#include <math.h>
#include <stdint.h>

#define BB 4
#define SS 2048
#define DDIM 1024
#define HH 16
#define HD 64

typedef __bf16 bf16x8 __attribute__((ext_vector_type(8)));
typedef float f32x4 __attribute__((ext_vector_type(4)));
typedef float f32x16 __attribute__((ext_vector_type(16)));
typedef int i32x4 __attribute__((ext_vector_type(4)));

// ---------------- helpers ----------------
__device__ __forceinline__ unsigned short f2bf(float f) {
    union { float f; unsigned u; } v; v.f = f;
    unsigned r = (v.u + 0x7FFFu + ((v.u >> 16) & 1u)) >> 16;
    return (unsigned short)r;
}
__device__ __forceinline__ float bf2f(unsigned short u) {
    union { unsigned u; float f; } v; v.u = ((unsigned)u) << 16;
    return v.f;
}
__device__ __forceinline__ void gload_lds16(const unsigned short* g, unsigned char* s) {
    __builtin_amdgcn_global_load_lds(
        (const __attribute__((address_space(1))) unsigned int*)(g),
        (__attribute__((address_space(3))) unsigned int*)(s), 16, 0, 0);
}

// ---------------- fp32 -> bf16 conversion ----------------
__global__ void cvt_f32_bf16(const float* __restrict__ in, unsigned short* __restrict__ outp, int n4) {
    int i = blockIdx.x * 256 + threadIdx.x;
    if (i >= n4) return;
    float4 v = ((const float4*)in)[i];
    ushort4 o;
    o.x = f2bf(v.x); o.y = f2bf(v.y); o.z = f2bf(v.z); o.w = f2bf(v.w);
    ((ushort4*)outp)[i] = o;
}

// ---------------- RoPE ----------------
__global__ void rope_table(float* __restrict__ cosT, float* __restrict__ sinT) {
    int idx = blockIdx.x * 256 + threadIdx.x;
    if (idx >= SS * 32) return;
    int s = idx >> 5;
    int j = idx & 31;
    float invf = powf(10000.0f, -(float)j / 32.0f);
    float ang = (float)s * invf;
    cosT[idx] = cosf(ang);
    sinT[idx] = sinf(ang);
}

__global__ void rope_bf16(unsigned short* __restrict__ t,
                          const float* __restrict__ cosT,
                          const float* __restrict__ sinT,
                          float scale) {
    int gid = blockIdx.x * 256 + threadIdx.x;   // B*S*512 pairs
    int row = gid >> 9;
    int p = gid & 511;
    int h = p >> 5, j = p & 31;
    int s = row & (SS - 1);
    size_t base = ((size_t)row << 10) + (h << 6) + j;
    float c = cosT[(s << 5) + j], sn = sinT[(s << 5) + j];
    float x1 = bf2f(t[base]), x2 = bf2f(t[base + 32]);
    t[base]      = f2bf((x1 * c - x2 * sn) * scale);
    t[base + 32] = f2bf((x2 * c + x1 * sn) * scale);
}

// ---------------------------------------------------------------------------
// bf16 MFMA GEMM, NT (unchanged from round 2; verified)
// ---------------------------------------------------------------------------
template <int OUT_BF16>
__global__ __launch_bounds__(256) void gemm_bf16_nt(const unsigned short* __restrict__ A,
                                                    const unsigned short* __restrict__ Bm,
                                                    void* __restrict__ C,
                                                    int M, int N, int K) {
    __shared__ unsigned char smem[16384];
    const int t = threadIdx.x;
    const int l = t & 63;
    const int w = t >> 6;
    const int wm = w >> 1, wn = w & 1;
    const int row0 = blockIdx.y * 128;
    const int col0 = blockIdx.x * 128;

    f32x4 zero4 = {0.f, 0.f, 0.f, 0.f};
    f32x4 acc[4][4];
#pragma unroll
    for (int i = 0; i < 4; ++i)
#pragma unroll
        for (int j = 0; j < 4; ++j) acc[i][j] = zero4;

    const int srow = w * 32 + (l >> 2);
    const int scol8 = ((l & 3) ^ ((l >> 3) & 3)) << 3;

    for (int k0 = 0; k0 < K; k0 += 32) {
        __syncthreads();
        const unsigned short* aSrc = A + (size_t)(row0 + srow) * K + k0 + scol8;
        const unsigned short* bSrc = Bm + (size_t)(col0 + srow) * K + k0 + scol8;
        gload_lds16(aSrc,                  smem + w * 2048);
        gload_lds16(aSrc + (size_t)16 * K, smem + w * 2048 + 1024);
        gload_lds16(bSrc,                  smem + 8192 + w * 2048);
        gload_lds16(bSrc + (size_t)16 * K, smem + 8192 + w * 2048 + 1024);
        __syncthreads();

        bf16x8 af[4], bf[4];
#pragma unroll
        for (int mi = 0; mi < 4; ++mi) {
            int o1 = (wm * 64 + mi * 16 + (l & 15)) * 64 + ((l >> 4) << 4);
            o1 ^= ((o1 >> 7) & 3) << 4;
            af[mi] = *(const bf16x8*)(smem + o1);
        }
#pragma unroll
        for (int ni = 0; ni < 4; ++ni) {
            int o1 = (wn * 64 + ni * 16 + (l & 15)) * 64 + ((l >> 4) << 4);
            o1 ^= ((o1 >> 7) & 3) << 4;
            bf[ni] = *(const bf16x8*)(smem + 8192 + o1);
        }
#pragma unroll
        for (int mi = 0; mi < 4; ++mi)
#pragma unroll
            for (int ni = 0; ni < 4; ++ni)
                acc[mi][ni] = __builtin_amdgcn_mfma_f32_16x16x32_bf16(af[mi], bf[ni], acc[mi][ni], 0, 0, 0);
    }

    const int cr = (l >> 4) << 2;
    const int cc = l & 15;
#pragma unroll
    for (int mi = 0; mi < 4; ++mi) {
#pragma unroll
        for (int ni = 0; ni < 4; ++ni) {
            int gcol = col0 + wn * 64 + ni * 16 + cc;
#pragma unroll
            for (int r = 0; r < 4; ++r) {
                int grow = row0 + wm * 64 + mi * 16 + cr + r;
                if (OUT_BF16)
                    ((unsigned short*)C)[(size_t)grow * N + gcol] = f2bf(acc[mi][ni][r]);
                else
                    ((float*)C)[(size_t)grow * N + gcol] = acc[mi][ni][r];
            }
        }
    }
}

// ---------------------------------------------------------------------------
// MFMA flash attention v2: swapped QK^T, in-register softmax (T12),
// defer-max (T13), 1-barrier pipelined K/Vt double-buffer (T14).
// Block: 4 warps x 32 q-rows = 128 q. KV tile = 64. 32x32x16 MFMA.
// LDS: K bufs [0,8K),[8K,16K); Vt bufs [16K,24K),[24K,32K); bcast [32K,+512)
// Q is pre-scaled by 0.125*log2(e) in its RoPE pass.
// ---------------------------------------------------------------------------
__global__ __launch_bounds__(256) void attn_mfma2(const unsigned short* __restrict__ qg,
                                                  const unsigned short* __restrict__ kg,
                                                  const unsigned short* __restrict__ vg,
                                                  unsigned short* __restrict__ og) {
    __shared__ unsigned char smem[33280];
    const int tid = threadIdx.x;
    const int ln = tid & 63;
    const int w = tid >> 6;
    const int lq = ln & 31;
    const int hi = ln >> 5;
    const int qb0 = blockIdx.x * 128;
    const int h = blockIdx.y, b = blockIdx.z;
    const int headoff = h * HD;
    const size_t bS = (size_t)b * SS;

    // ---- Q B-frags (B[k=d][col=q]): lane holds q=lq, d = dc*16 + hi*8 + j
    bf16x8 qf[4];
    {
        const unsigned short* qsrc = qg + (bS + qb0 + w * 32 + lq) * DDIM + headoff + hi * 8;
#pragma unroll
        for (int dc = 0; dc < 4; ++dc)
            qf[dc] = *(const bf16x8*)(qsrc + dc * 16);
    }

    f32x16 oacc[2];
#pragma unroll
    for (int i = 0; i < 2; ++i)
#pragma unroll
        for (int r = 0; r < 16; ++r) oacc[i][r] = 0.f;
    float m = -1e30f, lsum = 0.f;

    // staging geometry
    const int ksrow = w * 16 + (ln >> 3);            // + i*8
    const int kscol = ((ln & 7) ^ (ln >> 3)) << 3;   // pre-swizzled source col (elems)
    const unsigned short* kbase_g = kg + bS * DDIM + headoff;
    const int kp = ln & 31;                          // V: key pair
    const int db8 = w * 2 + hi;                      // V: d block (8 dims)
    const unsigned short* vbase_g = vg + bS * DDIM + headoff + db8 * 8;

    // ---- prologue: stage tile 0 into buf 0
    {
        const unsigned short* ksrc = kbase_g + (size_t)ksrow * DDIM + kscol;
        gload_lds16(ksrc,                    smem + w * 2048);
        gload_lds16(ksrc + (size_t)8 * DDIM, smem + w * 2048 + 1024);
        const unsigned short* vsrc = vbase_g + (size_t)(2 * kp) * DDIM;
        uint4 v0 = *(const uint4*)(vsrc);
        uint4 v1 = *(const uint4*)(vsrc + DDIM);
        asm volatile("s_waitcnt vmcnt(0)" ::: "memory");
        const unsigned* A0 = (const unsigned*)&v0;
        const unsigned* A1 = (const unsigned*)&v1;
#pragma unroll
        for (int i2 = 0; i2 < 4; ++i2) {
            unsigned a = A0[i2], bb = A1[i2];
            unsigned p0 = (a & 0xffffu) | (bb << 16);
            unsigned p1 = (a >> 16) | (bb & 0xffff0000u);
            int d0 = db8 * 8 + 2 * i2;
            int o0 = 16384 + ((d0 * 128 + kp * 4) ^ ((d0 & 7) << 4));
            int o1 = 16384 + (((d0 + 1) * 128 + kp * 4) ^ (((d0 + 1) & 7) << 4));
            *(unsigned*)(smem + o0) = p0;
            *(unsigned*)(smem + o1) = p1;
        }
    }
    __syncthreads();

    int cur = 0;
    for (int tkv = 0; tkv < SS / 64; ++tkv) {
        const int kcur = cur * 8192;
        const int vcur = 16384 + cur * 8192;
        const int nxt = cur ^ 1;
        const bool pre = (tkv + 1 < SS / 64);
        uint4 v0, v1;
        if (pre) {
            const int kv1 = (tkv + 1) * 64;
            const unsigned short* ksrc = kbase_g + (size_t)(kv1 + ksrow) * DDIM + kscol;
            gload_lds16(ksrc,                    smem + nxt * 8192 + w * 2048);
            gload_lds16(ksrc + (size_t)8 * DDIM, smem + nxt * 8192 + w * 2048 + 1024);
            const unsigned short* vsrc = vbase_g + (size_t)(kv1 + 2 * kp) * DDIM;
            v0 = *(const uint4*)(vsrc);
            v1 = *(const uint4*)(vsrc + DDIM);
        }

        // ---- S^T = K Q^T : st[kb], C[key][q], col=q=lq, row=crow(r,hi)
        f32x16 st[2];
#pragma unroll
        for (int kb = 0; kb < 2; ++kb) {
#pragma unroll
            for (int r = 0; r < 16; ++r) st[kb][r] = 0.f;
            bf16x8 kf[4];
#pragma unroll
            for (int dc = 0; dc < 4; ++dc) {
                int row = kb * 32 + lq;
                int o = kcur + ((row * 128 + dc * 32 + hi * 16) ^ ((row & 7) << 4));
                kf[dc] = *(const bf16x8*)(smem + o);
            }
#pragma unroll
            for (int dc = 0; dc < 4; ++dc)
                st[kb] = __builtin_amdgcn_mfma_f32_32x32x16_bf16(kf[dc], qf[dc], st[kb], 0, 0, 0);
        }

        // ---- online softmax (q = lq is lane-local; scores already *SC)
        float pm = st[0][0];
#pragma unroll
        for (int r = 1; r < 16; ++r) pm = fmaxf(pm, st[0][r]);
#pragma unroll
        for (int r = 0; r < 16; ++r) pm = fmaxf(pm, st[1][r]);
        pm = fmaxf(pm, __shfl_xor(pm, 32));

        if (__any(pm - m > 8.0f)) {           // T13 defer-max
            float mn = fmaxf(m, pm);
            float a2 = exp2f(m - mn);
            m = mn;
            lsum *= a2;
            if (ln < 32) *(float*)(smem + 32768 + w * 128 + lq * 4) = a2;
            asm volatile("s_waitcnt lgkmcnt(0)" ::: "memory");
#pragma unroll
            for (int r = 0; r < 16; ++r) {
                float a2r = *(const float*)(smem + 32768 + w * 128 +
                                            (((r & 3) + 8 * (r >> 2) + 4 * hi) << 2));
                oacc[0][r] *= a2r;
                oacc[1][r] *= a2r;
            }
        }

        // p = exp2(s - m); pack to PV A-frags via cvt_pk + permlane32_swap (T12)
        float rs = 0.f;
        i32x4 pwv[4];
#pragma unroll
        for (int g = 0; g < 4; ++g) {
            float pg[8];
#pragma unroll
            for (int j = 0; j < 8; ++j) {
                float sv = st[g >> 1][(g & 1) * 8 + j];
                pg[j] = exp2f(sv - m);
            }
#pragma unroll
            for (int j = 0; j < 8; ++j) rs += pg[j];
            unsigned u0, u1, u2, u3;
            asm("v_cvt_pk_bf16_f32 %0, %1, %2" : "=v"(u0) : "v"(pg[0]), "v"(pg[1]));
            asm("v_cvt_pk_bf16_f32 %0, %1, %2" : "=v"(u1) : "v"(pg[2]), "v"(pg[3]));
            asm("v_cvt_pk_bf16_f32 %0, %1, %2" : "=v"(u2) : "v"(pg[4]), "v"(pg[5]));
            asm("v_cvt_pk_bf16_f32 %0, %1, %2" : "=v"(u3) : "v"(pg[6]), "v"(pg[7]));
            asm("v_permlane32_swap_b32 %0, %1" : "+v"(u0), "+v"(u2));
            asm("v_permlane32_swap_b32 %0, %1" : "+v"(u1), "+v"(u3));
            pwv[g][0] = (int)u0; pwv[g][1] = (int)u1; pwv[g][2] = (int)u2; pwv[g][3] = (int)u3;
        }
        rs += __shfl_xor(rs, 32);
        lsum += rs;

        // ---- write next-tile Vt (after vmcnt: K-lds + V regs arrived) [T14]
        if (pre) {
            asm volatile("s_waitcnt vmcnt(0)" ::: "memory");
            const unsigned* A0 = (const unsigned*)&v0;
            const unsigned* A1 = (const unsigned*)&v1;
            const int vb_ = 16384 + nxt * 8192;
#pragma unroll
            for (int i2 = 0; i2 < 4; ++i2) {
                unsigned a = A0[i2], bb = A1[i2];
                unsigned p0 = (a & 0xffffu) | (bb << 16);
                unsigned p1 = (a >> 16) | (bb & 0xffff0000u);
                int d0 = db8 * 8 + 2 * i2;
                int o0 = vb_ + ((d0 * 128 + kp * 4) ^ ((d0 & 7) << 4));
                int o1 = vb_ + (((d0 + 1) * 128 + kp * 4) ^ (((d0 + 1) & 7) << 4));
                *(unsigned*)(smem + o0) = p0;
                *(unsigned*)(smem + o1) = p1;
            }
        }

        // ---- O += P V : A = pa[ks], B = Vt frags
#pragma unroll
        for (int dblk = 0; dblk < 2; ++dblk) {
#pragma unroll
            for (int ks = 0; ks < 4; ++ks) {
                int row = dblk * 32 + lq;
                int o = vcur + ((row * 128 + ks * 32 + hi * 16) ^ ((row & 7) << 4));
                bf16x8 vf = *(const bf16x8*)(smem + o);
                oacc[dblk] = __builtin_amdgcn_mfma_f32_32x32x16_bf16(
                    __builtin_bit_cast(bf16x8, pwv[ks]), vf, oacc[dblk], 0, 0, 0);
            }
        }
        __syncthreads();
        cur = nxt;
    }

    // ---- epilogue: O[q][d] /= l, q = crow(r,hi) via LDS broadcast
    {
        float inv = 1.0f / lsum;
        if (ln < 32) *(float*)(smem + 32768 + w * 128 + lq * 4) = inv;
        asm volatile("s_waitcnt lgkmcnt(0)" ::: "memory");
#pragma unroll
        for (int r = 0; r < 16; ++r) {
            int crow = (r & 3) + 8 * (r >> 2) + 4 * hi;
            float invr = *(const float*)(smem + 32768 + w * 128 + crow * 4);
            int grow = qb0 + w * 32 + crow;
            size_t base = (bS + grow) * DDIM + headoff + lq;
            og[base]      = f2bf(oacc[0][r] * invr);
            og[base + 32] = f2bf(oacc[1][r] * invr);
        }
    }
}

// ---------------------------------------------------------------------------
extern "C" void kernel_launch(void* const* d_in, const int* in_sizes, int n_in,
                              void* d_out, int out_size, void* d_ws, size_t ws_size,
                              hipStream_t stream) {
    const float* x  = (const float*)d_in[0];
    const float* Wq = (const float*)d_in[1];
    const float* Wk = (const float*)d_in[2];
    const float* Wv = (const float*)d_in[3];
    const float* Wo = (const float*)d_in[4];
    float* out = (float*)d_out;

    const size_t BSD = (size_t)BB * SS * DDIM;  // 8388608
    const size_t WSZ = (size_t)DDIM * DDIM;     // 1048576

    unsigned short* xb  = (unsigned short*)d_ws;
    unsigned short* wqb = xb + BSD;
    unsigned short* wkb = wqb + WSZ;
    unsigned short* wvb = wkb + WSZ;
    unsigned short* wob = wvb + WSZ;
    unsigned short* qb  = wob + WSZ;
    unsigned short* kb  = qb + BSD;
    unsigned short* vb  = kb + BSD;
    float* cosT = (float*)(vb + BSD);
    float* sinT = cosT + (size_t)SS * 32;
    unsigned short* ob = qb;  // attn output aliases qb (each block writes only its own Q region)

    const int M = BB * SS;  // 8192
    dim3 blk(256);
    dim3 gg(DDIM / 128, M / 128);  // (8, 64)

    const float QSCALE = 0.125f * 1.44269504089f;  // 1/sqrt(64) * log2(e)

    hipLaunchKernelGGL(rope_table, dim3((SS * 32 + 255) / 256), blk, 0, stream, cosT, sinT);
    hipLaunchKernelGGL(cvt_f32_bf16, dim3((unsigned)(BSD / 4 / 256)), blk, 0, stream, x, xb, (int)(BSD / 4));
    hipLaunchKernelGGL(cvt_f32_bf16, dim3((unsigned)(WSZ / 4 / 256)), blk, 0, stream, Wq, wqb, (int)(WSZ / 4));
    hipLaunchKernelGGL(cvt_f32_bf16, dim3((unsigned)(WSZ / 4 / 256)), blk, 0, stream, Wk, wkb, (int)(WSZ / 4));
    hipLaunchKernelGGL(cvt_f32_bf16, dim3((unsigned)(WSZ / 4 / 256)), blk, 0, stream, Wv, wvb, (int)(WSZ / 4));
    hipLaunchKernelGGL(cvt_f32_bf16, dim3((unsigned)(WSZ / 4 / 256)), blk, 0, stream, Wo, wob, (int)(WSZ / 4));

    hipLaunchKernelGGL((gemm_bf16_nt<1>), gg, blk, 0, stream, xb, wqb, (void*)qb, M, DDIM, DDIM);
    hipLaunchKernelGGL((gemm_bf16_nt<1>), gg, blk, 0, stream, xb, wkb, (void*)kb, M, DDIM, DDIM);
    hipLaunchKernelGGL((gemm_bf16_nt<1>), gg, blk, 0, stream, xb, wvb, (void*)vb, M, DDIM, DDIM);

    hipLaunchKernelGGL(rope_bf16, dim3(M * 512 / 256), blk, 0, stream, qb, cosT, sinT, QSCALE);
    hipLaunchKernelGGL(rope_bf16, dim3(M * 512 / 256), blk, 0, stream, kb, cosT, sinT, 1.0f);

    hipLaunchKernelGGL(attn_mfma2, dim3(SS / 128, HH, BB), blk, 0, stream, qb, kb, vb, ob);

    hipLaunchKernelGGL((gemm_bf16_nt<0>), gg, blk, 0, stream, ob, wob, (void*)out, M, DDIM, DDIM);
}